// Round 1
// baseline (302.790 us; speedup 1.0000x reference)
//
#include <hip/hip_runtime.h>
#include <cstdint>
#include <cmath>

#define B_ 4
#define H_ 256
#define C_ 80
#define TX_ 256
#define TY_ 1024
#define NEGF (-1e9f)
#define NEGD (-1e9)

// output layout (floats): o_en_ex [B,H,TY] | logp [B,TX,TY] | attn [B,TX,TY] | dr [B,TX]
#define OFF_LOGP (B_*H_*TY_)
#define OFF_ATTN (OFF_LOGP + B_*TX_*TY_)
#define OFF_DR   (OFF_ATTN + B_*TX_*TY_)

// ---------------------------------------------------------------------------
// Kernel A: logp[b,x,t] = -0.5*mean_c((y-mu)^2 * exp(-2 ls)) - 0.5*mean_c(ls)
// Also writes masked+transposed lpT[b,t,x] into the attn output region
// (scratch until k_attn overwrites it).  f64 accumulate to track the np ref.
// ---------------------------------------------------------------------------
__global__ __launch_bounds__(256) void k_logp(
    const float* __restrict__ mu, const float* __restrict__ ls,
    const float* __restrict__ y, const int* __restrict__ xlp,
    const int* __restrict__ ylp, float* __restrict__ logp_out,
    float* __restrict__ lpT)
{
  const int b  = blockIdx.y;
  const int x0 = blockIdx.x * 4;     // 4 x's per block
  const int tid = threadIdx.x;
  __shared__ double s_mu[4][C_];
  __shared__ double s_w[4][C_];
  __shared__ double s_t0[4];
  for (int i = tid; i < 4 * C_; i += 256) {
    int xi = i / C_, c = i - xi * C_;
    double m = (double)mu[(b * C_ + c) * TX_ + x0 + xi];
    double l = (double)ls[(b * C_ + c) * TX_ + x0 + xi];
    s_mu[xi][c] = m;
    s_w[xi][c]  = exp(-2.0 * l);
  }
  if (tid < 4) {
    double s = 0.0;
    for (int c = 0; c < C_; ++c) s += (double)ls[(b * C_ + c) * TX_ + x0 + tid];
    s_t0[tid] = -0.5 * (s * (1.0 / C_));
  }
  __syncthreads();

  const int t0 = tid * 4;
  double acc[4][4];
#pragma unroll
  for (int xi = 0; xi < 4; ++xi)
#pragma unroll
    for (int k = 0; k < 4; ++k) acc[xi][k] = 0.0;

  const float4* yp = (const float4*)(y + (size_t)b * C_ * TY_) + tid;
#pragma unroll 4
  for (int c = 0; c < C_; ++c) {
    float4 yv = yp[c * (TY_ / 4)];
    double y0 = yv.x, y1 = yv.y, y2 = yv.z, y3 = yv.w;
#pragma unroll
    for (int xi = 0; xi < 4; ++xi) {
      double m = s_mu[xi][c], w = s_w[xi][c];
      double d0 = y0 - m, d1 = y1 - m, d2 = y2 - m, d3 = y3 - m;
      acc[xi][0] = fma(d0 * d0, w, acc[xi][0]);
      acc[xi][1] = fma(d1 * d1, w, acc[xi][1]);
      acc[xi][2] = fma(d2 * d2, w, acc[xi][2]);
      acc[xi][3] = fma(d3 * d3, w, acc[xi][3]);
    }
  }

  const int xlen = xlp[b], ylen = ylp[b];
#pragma unroll
  for (int xi = 0; xi < 4; ++xi) {
    int x = x0 + xi;
    double c0 = s_t0[xi];
    float r[4];
#pragma unroll
    for (int k = 0; k < 4; ++k)
      r[k] = (float)(acc[xi][k] * (-0.5 / C_) + c0);
    *(float4*)&logp_out[((size_t)(b * TX_ + x)) * TY_ + t0] =
        make_float4(r[0], r[1], r[2], r[3]);
    bool xm = x < xlen;
#pragma unroll
    for (int k = 0; k < 4; ++k) {
      float v = (xm && (t0 + k) < ylen) ? r[k] : NEGF;
      lpT[((size_t)(b * TY_) + t0 + k) * TX_ + x] = v;
    }
  }
}

// ---------------------------------------------------------------------------
// Kernel B: Viterbi DP. One wave64 per batch; lane holds x = 4*lane+j in f64.
// Diag bits packed column-major in LDS (bits[x][t/32], padded stride 33).
// Backward = run-length walk over columns (find highest set bit <= t).
// Emits durations (dr output), inclusive cumsum (ws) and t->x map (ws).
// ---------------------------------------------------------------------------
__global__ __launch_bounds__(64) void k_dp(
    const float* __restrict__ lpT, const int* __restrict__ xlp,
    const int* __restrict__ ylp, float* __restrict__ dr_out,
    int* __restrict__ cum_ws, int* __restrict__ xt_ws)
{
  const int b = blockIdx.x;
  const int lane = threadIdx.x;
  __shared__ uint32_t bits[TX_][33];
  __shared__ uint32_t dur[TX_];

  const float4* colp = (const float4*)(lpT + (size_t)b * TY_ * TX_) + lane;
  double v0 = (lane == 0) ? 0.0 : NEGD, v1 = NEGD, v2 = NEGD, v3 = NEGD;
  uint32_t b0 = 0, b1 = 0, b2 = 0, b3 = 0;

  float4 q[8];
#pragma unroll
  for (int i = 0; i < 8; ++i) q[i] = colp[i * (TX_ / 4)];
#pragma unroll
  for (int j = 0; j < 4; ++j) dur[4 * lane + j] = 0;

#pragma unroll 8
  for (int t = 0; t < TY_; ++t) {
    float4 c = q[t & 7];
    if (t + 8 < TY_) q[t & 7] = colp[(t + 8) * (TX_ / 4)];
    double sh  = __shfl_up(v3, 1);
    double vs0 = (lane == 0) ? NEGD : sh;
    uint32_t bit = 1u << (t & 31);
    if (vs0 > v0) b0 |= bit;      // diag = v_shift > v  (pre-update carry)
    if (v0 > v1)  b1 |= bit;
    if (v1 > v2)  b2 |= bit;
    if (v2 > v3)  b3 |= bit;
    double nv0 = (double)c.x + fmax(v0, vs0);
    double nv1 = (double)c.y + fmax(v1, v0);
    double nv2 = (double)c.z + fmax(v2, v1);
    double nv3 = (double)c.w + fmax(v3, v2);
    v0 = nv0; v1 = nv1; v2 = nv2; v3 = nv3;
    if ((t & 31) == 31) {
      int w = t >> 5;
      bits[4 * lane + 0][w] = b0; bits[4 * lane + 1][w] = b1;
      bits[4 * lane + 2][w] = b2; bits[4 * lane + 3][w] = b3;
      b0 = b1 = b2 = b3 = 0;
    }
  }
  __syncthreads();

  const int xlen = xlp[b], ylen = ylp[b];
  if (lane == 0) {
    int idx = xlen - 1;
    int t = ylen - 1;
    while (t >= 0) {
      if (idx == 0) { dur[0] += (uint32_t)(t + 1); break; }
      int w = t >> 5, r = t & 31;
      uint32_t word = bits[idx][w];
      word &= (r == 31) ? 0xffffffffu : ((1u << (r + 1)) - 1u);
      while (word == 0 && w > 0) { --w; word = bits[idx][w]; }
      if (word == 0) { dur[idx] += (uint32_t)(t + 1); break; }
      int bitpos = 31 - __builtin_clz(word);
      int tp = (w << 5) | bitpos;          // step where diag fires -> decrement
      dur[idx] += (uint32_t)(t - tp + 1);
      --idx;
      t = tp - 1;
    }
  }
  __syncthreads();

  // wave-wide inclusive scan of durations -> cum, dr, and t->x scatter map
  uint32_t d0 = dur[4 * lane], d1 = dur[4 * lane + 1];
  uint32_t d2 = dur[4 * lane + 2], d3 = dur[4 * lane + 3];
  uint32_t own = d0 + d1 + d2 + d3;
  uint32_t s = own;
#pragma unroll
  for (int off = 1; off < 64; off <<= 1) {
    uint32_t n = __shfl_up(s, off);
    if (lane >= off) s += n;
  }
  uint32_t base = s - own;
  uint32_t c0 = base + d0, c1 = c0 + d1, c2 = c1 + d2, c3 = c2 + d3;
  int x = 4 * lane;
  cum_ws[b * TX_ + x]     = (int)c0;
  cum_ws[b * TX_ + x + 1] = (int)c1;
  cum_ws[b * TX_ + x + 2] = (int)c2;
  cum_ws[b * TX_ + x + 3] = (int)c3;
  dr_out[b * TX_ + x]     = (float)d0;
  dr_out[b * TX_ + x + 1] = (float)d1;
  dr_out[b * TX_ + x + 2] = (float)d2;
  dr_out[b * TX_ + x + 3] = (float)d3;
  int* xt = xt_ws + b * TY_;
  for (uint32_t t = c0 - d0; t < c0; ++t) xt[t] = x;
  for (uint32_t t = c1 - d1; t < c1; ++t) xt[t] = x + 1;
  for (uint32_t t = c2 - d2; t < c2; ++t) xt[t] = x + 2;
  for (uint32_t t = c3 - d3; t < c3; ++t) xt[t] = x + 3;
}

// ---------------------------------------------------------------------------
// Kernel C: attn[b,x,t] = (cum[x-1] <= t < cum[x])  (== MAS path == gen_path)
// ---------------------------------------------------------------------------
__global__ __launch_bounds__(256) void k_attn(
    const int* __restrict__ cum_ws, float* __restrict__ attn)
{
  const int b = blockIdx.y, x = blockIdx.x, tid = threadIdx.x;
  int hi = cum_ws[b * TX_ + x];
  int lo = (x > 0) ? cum_ws[b * TX_ + x - 1] : 0;
  int t0 = tid * 4;
  float4 v;
  v.x = (t0     >= lo && t0     < hi) ? 1.f : 0.f;
  v.y = (t0 + 1 >= lo && t0 + 1 < hi) ? 1.f : 0.f;
  v.z = (t0 + 2 >= lo && t0 + 2 < hi) ? 1.f : 0.f;
  v.w = (t0 + 3 >= lo && t0 + 3 < hi) ? 1.f : 0.f;
  *(float4*)&attn[((size_t)(b * TX_ + x)) * TY_ + t0] = v;
}

// ---------------------------------------------------------------------------
// Kernel D: o_en_ex[b,h,t] = t < ylen ? en[b,h,xt[b,t]] : 0   (path is one-hot)
// ---------------------------------------------------------------------------
__global__ __launch_bounds__(256) void k_gather(
    const float* __restrict__ en, const int* __restrict__ xt_ws,
    const int* __restrict__ ylp, float* __restrict__ oen)
{
  const int b = blockIdx.y, h = blockIdx.x, tid = threadIdx.x;
  __shared__ float row[TX_];
  row[tid] = en[((size_t)(b * H_ + h)) * TX_ + tid];
  __syncthreads();
  const int ylen = ylp[b];
  int t0 = tid * 4;
  int4 xi = *(const int4*)&xt_ws[b * TY_ + t0];
  float4 v;
  v.x = (t0     < ylen) ? row[xi.x & (TX_ - 1)] : 0.f;
  v.y = (t0 + 1 < ylen) ? row[xi.y & (TX_ - 1)] : 0.f;
  v.z = (t0 + 2 < ylen) ? row[xi.z & (TX_ - 1)] : 0.f;
  v.w = (t0 + 3 < ylen) ? row[xi.w & (TX_ - 1)] : 0.f;
  *(float4*)&oen[((size_t)(b * H_ + h)) * TY_ + t0] = v;
}

extern "C" void kernel_launch(void* const* d_in, const int* in_sizes, int n_in,
                              void* d_out, int out_size, void* d_ws, size_t ws_size,
                              hipStream_t stream)
{
  const float* en = (const float*)d_in[0];
  const float* mu = (const float*)d_in[1];
  const float* ls = (const float*)d_in[2];
  const float* y  = (const float*)d_in[3];
  const int*   xl = (const int*)d_in[4];
  const int*   yl = (const int*)d_in[5];

  float* out  = (float*)d_out;
  float* oen  = out;             // [B,H,TY]
  float* logp = out + OFF_LOGP;  // [B,TX,TY]
  float* attn = out + OFF_ATTN;  // [B,TX,TY] (doubles as lpT scratch first)
  float* dr   = out + OFF_DR;    // [B,TX]

  int* cum = (int*)d_ws;         // B*TX ints
  int* xt  = cum + B_ * TX_;     // B*TY ints

  k_logp  <<<dim3(TX_ / 4, B_), 256, 0, stream>>>(mu, ls, y, xl, yl, logp, attn);
  k_dp    <<<B_,              64, 0, stream>>>(attn, xl, yl, dr, cum, xt);
  k_attn  <<<dim3(TX_, B_),  256, 0, stream>>>(cum, attn);
  k_gather<<<dim3(H_, B_),   256, 0, stream>>>(en, xt, yl, oen);
}